// Round 1
// baseline (2113.955 us; speedup 1.0000x reference)
//
#include <hip/hip_runtime.h>
#include <math.h>

#define N_ROWS   16384
#define K_EMB    8192
#define C_DIM    256
#define QUANT_N  4194304      // 16*256*32*32
#define QUANT_OFF 1
#define PERP_OFF  4194305
#define ENC_OFF   4194306

// ws layout in 4-byte units
#define WS_BK    0            // 8192 f32
#define WS_MINV  8192         // 32768 f32  ([n][2])
#define WS_MINI  40960        // 32768 i32
#define WS_IDX   73728        // 16384 i32
#define WS_CNT   90112        // 8192 i32
#define WS_ACC   98304        // 1 double (16B reserved)

// ---------------- b_k = sum(emb[k,:]^2) ----------------
__global__ void vq_bk_kernel(const float* __restrict__ emb, float* __restrict__ bk) {
    int row  = blockIdx.x * 4 + (threadIdx.x >> 6);
    int lane = threadIdx.x & 63;
    float4 v = reinterpret_cast<const float4*>(emb)[(size_t)row * 64 + lane];
    float s = v.x * v.x + v.y * v.y + v.z * v.z + v.w * v.w;
#pragma unroll
    for (int o = 32; o > 0; o >>= 1) s += __shfl_down(s, o, 64);
    if (lane == 0) bk[row] = s;
}

// ---------------- main distance/argmin GEMM ----------------
// grid 256: blockIdx>>1 = row block (128 rows), blockIdx&1 = K split (4096 each)
__launch_bounds__(256, 2)
__global__ void vq_argmin_kernel(const float* __restrict__ xin,
                                 const float* __restrict__ emb,
                                 const float* __restrict__ bk,
                                 float* __restrict__ minv_ws,
                                 int* __restrict__ mini_ws) {
    __shared__ float x_lds[128][68];
    __shared__ float e_lds[128][68];
    __shared__ float a_lds[128];

    const int tid = threadIdx.x;
    const int tr  = tid & 15;    // row-group 0..15
    const int tk  = tid >> 4;    // k-group 0..15
    const int rb     = blockIdx.x >> 1;
    const int split  = blockIdx.x & 1;
    const int row0   = rb * 128;
    const int b_img  = row0 >> 10;         // batch index (1024 rows per image)
    const int n_off  = row0 & 1023;
    // flat[(row, c)] = inputs[b][c][h][w] = xin[b*256*1024 + c*1024 + (row&1023)]
    const float* xbase = xin + (size_t)b_img * (C_DIM * 1024) + n_off;

    float minv[8];
    int   mini[8];
    float a_reg[8];
#pragma unroll
    for (int rr = 0; rr < 8; ++rr) { minv[rr] = 3.402823466e38f; mini[rr] = 0; a_reg[rr] = 0.f; }
    if (tid < 128) a_lds[tid] = 0.f;

    const int k_begin = split * 4096;
    float m[8][8];

    for (int kt = 0; kt < 32; ++kt) {
        const int k0 = k_begin + kt * 128;
#pragma unroll
        for (int rr = 0; rr < 8; ++rr)
#pragma unroll
            for (int kk = 0; kk < 8; ++kk) m[rr][kk] = 0.f;

        for (int cc = 0; cc < 4; ++cc) {
            __syncthreads();
            // stage x tile: 128 rows x 64 c (coalesced: 128 consecutive rows contiguous)
            for (int i = tid; i < 128 * 64; i += 256) {
                int r = i & 127;
                int c = i >> 7;
                x_lds[r][c] = xbase[(size_t)(cc * 64 + c) * 1024 + r];
            }
            // stage e tile: 128 k x 64 c via float4
            {
                int c4  = tid & 15;
                int kk0 = tid >> 4;
#pragma unroll
                for (int p = 0; p < 8; ++p) {
                    int k = kk0 + p * 16;
                    float4 v = reinterpret_cast<const float4*>(emb)[(size_t)(k0 + k) * 64 + cc * 16 + c4];
                    *reinterpret_cast<float4*>(&e_lds[k][c4 * 4]) = v;
                }
            }
            __syncthreads();
            if (kt == 0 && tid < 128) {
                // row sums of x^2, strict ascending-c order
                float s = a_lds[tid];
                for (int c = 0; c < 64; ++c) { float xv = x_lds[tid][c]; s += xv * xv; }
                a_lds[tid] = s;
            }
            // compute: 8x8 micro-tile, float4 over c
            for (int c4 = 0; c4 < 16; ++c4) {
                float4 xv[8], ev[8];
#pragma unroll
                for (int rr = 0; rr < 8; ++rr)
                    xv[rr] = *reinterpret_cast<const float4*>(&x_lds[tr + rr * 16][c4 * 4]);
#pragma unroll
                for (int kk = 0; kk < 8; ++kk)
                    ev[kk] = *reinterpret_cast<const float4*>(&e_lds[tk + kk * 16][c4 * 4]);
#pragma unroll
                for (int rr = 0; rr < 8; ++rr)
#pragma unroll
                    for (int kk = 0; kk < 8; ++kk) {
                        m[rr][kk] += xv[rr].x * ev[kk].x;
                        m[rr][kk] += xv[rr].y * ev[kk].y;
                        m[rr][kk] += xv[rr].z * ev[kk].z;
                        m[rr][kk] += xv[rr].w * ev[kk].w;
                    }
            }
        }
        __syncthreads();   // a_lds complete (kt==0) before epilogue
        if (kt == 0) {
#pragma unroll
            for (int rr = 0; rr < 8; ++rr) a_reg[rr] = a_lds[tr + rr * 16];
        }
        // epilogue: d = fl(fl(a + b_k) - 2*m), running first-min
#pragma unroll
        for (int kk = 0; kk < 8; ++kk) {
            int kl = tk + kk * 16;
            float b = bk[k0 + kl];
#pragma unroll
            for (int rr = 0; rr < 8; ++rr) {
                float t = a_reg[rr] + b;
                float d = t - 2.0f * m[rr][kk];
                if (d < minv[rr]) { minv[rr] = d; mini[rr] = k0 + kl; }
            }
        }
    }

    // cross-thread (over tk) reduce with first-index tie-break
    __syncthreads();
    float (*pv)[16] = reinterpret_cast<float(*)[16]>(&x_lds[0][0]);
    int   (*pi)[16] = reinterpret_cast<int(*)[16]>(&e_lds[0][0]);
#pragma unroll
    for (int rr = 0; rr < 8; ++rr) {
        pv[tr + rr * 16][tk] = minv[rr];
        pi[tr + rr * 16][tk] = mini[rr];
    }
    __syncthreads();
    if (tid < 128) {
        float bv = pv[tid][0];
        int   bi = pi[tid][0];
#pragma unroll
        for (int j = 1; j < 16; ++j) {
            float v = pv[tid][j];
            int   i = pi[tid][j];
            if (v < bv || (v == bv && i < bi)) { bv = v; bi = i; }
        }
        int n = row0 + tid;
        minv_ws[n * 2 + split] = bv;
        mini_ws[n * 2 + split] = bi;
    }
}

// ---------------- combine splits, histogram, one-hot scatter ----------------
__global__ void vq_combine_kernel(const float* __restrict__ minv_ws,
                                  const int* __restrict__ mini_ws,
                                  int* __restrict__ idx_ws,
                                  int* __restrict__ counts,
                                  float* __restrict__ enc) {
    int n = blockIdx.x * 256 + threadIdx.x;
    if (n >= N_ROWS) return;
    float v0 = minv_ws[n * 2], v1 = minv_ws[n * 2 + 1];
    int   i0 = mini_ws[n * 2], i1 = mini_ws[n * 2 + 1];
    int best = (v1 < v0) ? i1 : i0;   // tie -> i0 (smaller index, split0 < split1)
    idx_ws[n] = best;
    atomicAdd(&counts[best], 1);
    enc[(size_t)n * K_EMB + best] = 1.0f;
}

// ---------------- quantized output + loss reduction ----------------
__global__ void vq_quant_loss_kernel(const float* __restrict__ xin,
                                     const float* __restrict__ emb,
                                     const int* __restrict__ idx_ws,
                                     float* __restrict__ out,
                                     double* __restrict__ acc) {
    double local = 0.0;
    for (int id = blockIdx.x * 256 + threadIdx.x; id < QUANT_N; id += gridDim.x * 256) {
        int n = (id & 1023) | ((id >> 18) << 10);   // b*1024 + h*32 + w
        int c = (id >> 10) & 255;
        int k = idx_ws[n];
        float q  = emb[(size_t)k * C_DIM + c];
        float x  = xin[id];
        float dq = q - x;                 // fl(q - x)
        out[QUANT_OFF + id] = x + dq;     // straight-through: fl(x + fl(q-x))
        local += (double)(dq * dq);
    }
#pragma unroll
    for (int o = 32; o > 0; o >>= 1) local += __shfl_down(local, o, 64);
    __shared__ double wsum[4];
    if ((threadIdx.x & 63) == 0) wsum[threadIdx.x >> 6] = local;
    __syncthreads();
    if (threadIdx.x == 0) atomicAdd(acc, wsum[0] + wsum[1] + wsum[2] + wsum[3]);
}

// ---------------- perplexity + loss finalize ----------------
__global__ void vq_finalize_kernel(const int* __restrict__ counts,
                                   const double* __restrict__ acc,
                                   float* __restrict__ out) {
    double s = 0.0;
    for (int k = threadIdx.x; k < K_EMB; k += 256) {
        int c = counts[k];
        if (c > 0) {
            double p = (double)c * (1.0 / 16384.0);
            s += p * log(p + 1e-10);
        }
    }
#pragma unroll
    for (int o = 32; o > 0; o >>= 1) s += __shfl_down(s, o, 64);
    __shared__ double wsum[4];
    if ((threadIdx.x & 63) == 0) wsum[threadIdx.x >> 6] = s;
    __syncthreads();
    if (threadIdx.x == 0) {
        double tot = wsum[0] + wsum[1] + wsum[2] + wsum[3];
        out[PERP_OFF] = (float)exp(-tot);
        float l = (float)(acc[0] * (1.0 / (double)QUANT_N));
        out[0] = l + 0.25f * l;   // q_latent + 0.25 * e_latent (numerically equal arrays)
    }
}

extern "C" void kernel_launch(void* const* d_in, const int* in_sizes, int n_in,
                              void* d_out, int out_size, void* d_ws, size_t ws_size,
                              hipStream_t stream) {
    const float* xin = (const float*)d_in[0];
    const float* emb = (const float*)d_in[1];
    float* out = (float*)d_out;
    float* ws  = (float*)d_ws;

    float*  bk      = ws + WS_BK;
    float*  minv_ws = ws + WS_MINV;
    int*    mini_ws = (int*)(ws + WS_MINI);
    int*    idx_ws  = (int*)(ws + WS_IDX);
    int*    counts  = (int*)(ws + WS_CNT);
    double* acc     = (double*)(ws + WS_ACC);

    // zero the one-hot region, histogram, and loss accumulator
    hipMemsetAsync(out + ENC_OFF, 0, (size_t)N_ROWS * K_EMB * sizeof(float), stream);
    hipMemsetAsync(counts, 0, K_EMB * sizeof(int), stream);
    hipMemsetAsync(acc, 0, 16, stream);

    vq_bk_kernel<<<K_EMB / 4, 256, 0, stream>>>(emb, bk);
    vq_argmin_kernel<<<256, 256, 0, stream>>>(xin, emb, bk, minv_ws, mini_ws);
    vq_combine_kernel<<<N_ROWS / 256, 256, 0, stream>>>(minv_ws, mini_ws, idx_ws, counts, out + ENC_OFF);
    vq_quant_loss_kernel<<<2048, 256, 0, stream>>>(xin, emb, idx_ws, out, acc);
    vq_finalize_kernel<<<1, 256, 0, stream>>>(counts, acc, out);
}

// Round 2
// 1421.544 us; speedup vs baseline: 1.4871x; 1.4871x over previous
//
#include <hip/hip_runtime.h>
#include <math.h>

#define N_ROWS   16384
#define K_EMB    8192
#define C_DIM    256
#define QUANT_N  4194304      // 16*256*32*32
#define QUANT_OFF 1
#define PERP_OFF  4194305
#define ENC_OFF   4194306

#define NSPLIT   4            // K split factor (grid = 128 rowblocks * NSPLIT)

// ws layout in 4-byte units
#define WS_BK    0            // 8192 f32
#define WS_MINV  8192         // 16384*NSPLIT f32
#define WS_MINI  (WS_MINV + N_ROWS * NSPLIT)   // 16384*NSPLIT i32
#define WS_IDX   (WS_MINI + N_ROWS * NSPLIT)   // 16384 i32
#define WS_CNT   (WS_IDX + N_ROWS)             // 8192 i32
#define WS_ACC   (WS_CNT + K_EMB + 64)         // 1 double

// ---------------- b_k = sum(emb[k,:]^2) ----------------
__global__ void vq_bk_kernel(const float* __restrict__ emb, float* __restrict__ bk) {
    int row  = blockIdx.x * 4 + (threadIdx.x >> 6);
    int lane = threadIdx.x & 63;
    float4 v = reinterpret_cast<const float4*>(emb)[(size_t)row * 64 + lane];
    float s = v.x * v.x + v.y * v.y + v.z * v.z + v.w * v.w;
#pragma unroll
    for (int o = 32; o > 0; o >>= 1) s += __shfl_down(s, o, 64);
    if (lane == 0) bk[row] = s;
}

// ---------------- main distance/argmin GEMM ----------------
// grid 512: blockIdx>>2 = row block (128 rows), blockIdx&3 = K split (2048 each)
// block tile: 128 rows x 256 ks, microtile 8 rows x 16 ks, c staged in 32-chunks
__launch_bounds__(256, 2)
__global__ void vq_argmin_kernel(const float* __restrict__ xin,
                                 const float* __restrict__ emb,
                                 const float* __restrict__ bk,
                                 float* __restrict__ minv_ws,
                                 int* __restrict__ mini_ws) {
    __shared__ float x_lds[128][36];
    __shared__ float e_lds[256][36];
    __shared__ float a_lds[128];

    const int tid = threadIdx.x;
    const int tr  = tid & 15;    // row-group 0..15
    const int tk  = tid >> 4;    // k-group 0..15
    const int rb     = blockIdx.x >> 2;
    const int split  = blockIdx.x & (NSPLIT - 1);
    const int row0   = rb * 128;
    const int b_img  = row0 >> 10;         // batch index (1024 rows per image)
    const int n_off  = row0 & 1023;
    // flat[(row, c)] = inputs[b][c][h][w] = xin[b*256*1024 + c*1024 + (row&1023)]
    const float* xbase = xin + (size_t)b_img * (C_DIM * 1024) + n_off;

    float minv[8];
    int   mini[8];
    float a_reg[8];
#pragma unroll
    for (int rr = 0; rr < 8; ++rr) { minv[rr] = 3.402823466e38f; mini[rr] = 0; a_reg[rr] = 0.f; }
    if (tid < 128) a_lds[tid] = 0.f;

    const int k_begin = split * (K_EMB / NSPLIT);
    float m[8][16];

    for (int kt = 0; kt < (K_EMB / NSPLIT) / 256; ++kt) {
        const int k0 = k_begin + kt * 256;
#pragma unroll
        for (int rr = 0; rr < 8; ++rr)
#pragma unroll
            for (int kk = 0; kk < 16; ++kk) m[rr][kk] = 0.f;

        for (int cc = 0; cc < 8; ++cc) {
            __syncthreads();
            // stage x tile: 128 rows x 32 c (coalesced in rows)
            {
                int r = tid & 127;
                int c = tid >> 7;
#pragma unroll
                for (int p = 0; p < 16; ++p)
                    x_lds[r][c + p * 2] = xbase[(size_t)(cc * 32 + c + p * 2) * 1024 + r];
            }
            // stage e tile: 256 k x 32 c via float4 (8 float4 per k-row)
            {
#pragma unroll
                for (int p = 0; p < 8; ++p) {
                    int idx = tid + p * 256;
                    int k   = idx >> 3;
                    int c4  = idx & 7;
                    float4 v = reinterpret_cast<const float4*>(emb)[(size_t)(k0 + k) * 64 + cc * 8 + c4];
                    *reinterpret_cast<float4*>(&e_lds[k][c4 * 4]) = v;
                }
            }
            __syncthreads();
            if (kt == 0 && tid < 128) {
                // row sums of x^2, strict ascending-c order (bitwise == round-1 scheme)
                float s = a_lds[tid];
                for (int c = 0; c < 32; ++c) { float xv = x_lds[tid][c]; s += xv * xv; }
                a_lds[tid] = s;
            }
            // compute: 8x16 micro-tile, float4 over c, ev staged in two halves of 8
            for (int c4 = 0; c4 < 8; ++c4) {
                float4 xv[8];
#pragma unroll
                for (int rr = 0; rr < 8; ++rr)
                    xv[rr] = *reinterpret_cast<const float4*>(&x_lds[tr + rr * 16][c4 * 4]);
                {
                    float4 ev[8];
#pragma unroll
                    for (int kk = 0; kk < 8; ++kk)
                        ev[kk] = *reinterpret_cast<const float4*>(&e_lds[tk + kk * 16][c4 * 4]);
#pragma unroll
                    for (int rr = 0; rr < 8; ++rr)
#pragma unroll
                        for (int kk = 0; kk < 8; ++kk) {
                            m[rr][kk] += xv[rr].x * ev[kk].x;
                            m[rr][kk] += xv[rr].y * ev[kk].y;
                            m[rr][kk] += xv[rr].z * ev[kk].z;
                            m[rr][kk] += xv[rr].w * ev[kk].w;
                        }
                }
                {
                    float4 ev[8];
#pragma unroll
                    for (int kk = 0; kk < 8; ++kk)
                        ev[kk] = *reinterpret_cast<const float4*>(&e_lds[128 + tk + kk * 16][c4 * 4]);
#pragma unroll
                    for (int rr = 0; rr < 8; ++rr)
#pragma unroll
                        for (int kk = 0; kk < 8; ++kk) {
                            m[rr][kk + 8] += xv[rr].x * ev[kk].x;
                            m[rr][kk + 8] += xv[rr].y * ev[kk].y;
                            m[rr][kk + 8] += xv[rr].z * ev[kk].z;
                            m[rr][kk + 8] += xv[rr].w * ev[kk].w;
                        }
                }
            }
        }
        if (kt == 0) {
            __syncthreads();   // a_lds complete before epilogue reads
#pragma unroll
            for (int rr = 0; rr < 8; ++rr) a_reg[rr] = a_lds[tr + rr * 16];
        }
        // epilogue: d = fl(fl(a + b_k) - 2*m), running first-min (k ascending per thread)
#pragma unroll
        for (int kk = 0; kk < 16; ++kk) {
            int kl = tk + kk * 16;
            float b = bk[k0 + kl];
#pragma unroll
            for (int rr = 0; rr < 8; ++rr) {
                float t = a_reg[rr] + b;
                float d = t - 2.0f * m[rr][kk];
                if (d < minv[rr]) { minv[rr] = d; mini[rr] = k0 + kl; }
            }
        }
    }

    // cross-thread (over tk) reduce with first-index tie-break
    __syncthreads();
    float (*pv)[16] = reinterpret_cast<float(*)[16]>(&x_lds[0][0]);
    int   (*pi)[16] = reinterpret_cast<int(*)[16]>(&e_lds[0][0]);
#pragma unroll
    for (int rr = 0; rr < 8; ++rr) {
        pv[tr + rr * 16][tk] = minv[rr];
        pi[tr + rr * 16][tk] = mini[rr];
    }
    __syncthreads();
    if (tid < 128) {
        float bv = pv[tid][0];
        int   bi = pi[tid][0];
#pragma unroll
        for (int j = 1; j < 16; ++j) {
            float v = pv[tid][j];
            int   i = pi[tid][j];
            if (v < bv || (v == bv && i < bi)) { bv = v; bi = i; }
        }
        int n = row0 + tid;
        minv_ws[n * NSPLIT + split] = bv;
        mini_ws[n * NSPLIT + split] = bi;
    }
}

// ---------------- combine splits, histogram, one-hot scatter ----------------
__global__ void vq_combine_kernel(const float* __restrict__ minv_ws,
                                  const int* __restrict__ mini_ws,
                                  int* __restrict__ idx_ws,
                                  int* __restrict__ counts,
                                  float* __restrict__ enc) {
    int n = blockIdx.x * 256 + threadIdx.x;
    if (n >= N_ROWS) return;
    float bv = minv_ws[n * NSPLIT];
    int   bi = mini_ws[n * NSPLIT];
#pragma unroll
    for (int s = 1; s < NSPLIT; ++s) {
        float v = minv_ws[n * NSPLIT + s];
        int   i = mini_ws[n * NSPLIT + s];
        if (v < bv) { bv = v; bi = i; }   // tie -> earlier split = smaller index
    }
    idx_ws[n] = bi;
    atomicAdd(&counts[bi], 1);
    enc[(size_t)n * K_EMB + bi] = 1.0f;
}

// ---------------- quantized output + loss reduction ----------------
__global__ void vq_quant_loss_kernel(const float* __restrict__ xin,
                                     const float* __restrict__ emb,
                                     const int* __restrict__ idx_ws,
                                     float* __restrict__ out,
                                     double* __restrict__ acc) {
    double local = 0.0;
    for (int id = blockIdx.x * 256 + threadIdx.x; id < QUANT_N; id += gridDim.x * 256) {
        int n = (id & 1023) | ((id >> 18) << 10);   // b*1024 + h*32 + w
        int c = (id >> 10) & 255;
        int k = idx_ws[n];
        float q  = emb[(size_t)k * C_DIM + c];
        float x  = xin[id];
        float dq = q - x;                 // fl(q - x)
        out[QUANT_OFF + id] = x + dq;     // straight-through: fl(x + fl(q-x))
        local += (double)(dq * dq);
    }
#pragma unroll
    for (int o = 32; o > 0; o >>= 1) local += __shfl_down(local, o, 64);
    __shared__ double wsum[4];
    if ((threadIdx.x & 63) == 0) wsum[threadIdx.x >> 6] = local;
    __syncthreads();
    if (threadIdx.x == 0) atomicAdd(acc, wsum[0] + wsum[1] + wsum[2] + wsum[3]);
}

// ---------------- perplexity + loss finalize ----------------
__global__ void vq_finalize_kernel(const int* __restrict__ counts,
                                   const double* __restrict__ acc,
                                   float* __restrict__ out) {
    double s = 0.0;
    for (int k = threadIdx.x; k < K_EMB; k += 256) {
        int c = counts[k];
        if (c > 0) {
            double p = (double)c * (1.0 / 16384.0);
            s += p * log(p + 1e-10);
        }
    }
#pragma unroll
    for (int o = 32; o > 0; o >>= 1) s += __shfl_down(s, o, 64);
    __shared__ double wsum[4];
    if ((threadIdx.x & 63) == 0) wsum[threadIdx.x >> 6] = s;
    __syncthreads();
    if (threadIdx.x == 0) {
        double tot = wsum[0] + wsum[1] + wsum[2] + wsum[3];
        out[PERP_OFF] = (float)exp(-tot);
        float l = (float)(acc[0] * (1.0 / (double)QUANT_N));
        out[0] = l + 0.25f * l;   // q_latent + 0.25 * e_latent (numerically equal arrays)
    }
}

extern "C" void kernel_launch(void* const* d_in, const int* in_sizes, int n_in,
                              void* d_out, int out_size, void* d_ws, size_t ws_size,
                              hipStream_t stream) {
    const float* xin = (const float*)d_in[0];
    const float* emb = (const float*)d_in[1];
    float* out = (float*)d_out;
    float* ws  = (float*)d_ws;

    float*  bk      = ws + WS_BK;
    float*  minv_ws = ws + WS_MINV;
    int*    mini_ws = (int*)(ws + WS_MINI);
    int*    idx_ws  = (int*)(ws + WS_IDX);
    int*    counts  = (int*)(ws + WS_CNT);
    double* acc     = (double*)(ws + WS_ACC);

    // zero the one-hot region, histogram, and loss accumulator
    hipMemsetAsync(out + ENC_OFF, 0, (size_t)N_ROWS * K_EMB * sizeof(float), stream);
    hipMemsetAsync(counts, 0, K_EMB * sizeof(int), stream);
    hipMemsetAsync(acc, 0, 16, stream);

    vq_bk_kernel<<<K_EMB / 4, 256, 0, stream>>>(emb, bk);
    vq_argmin_kernel<<<128 * NSPLIT, 256, 0, stream>>>(xin, emb, bk, minv_ws, mini_ws);
    vq_combine_kernel<<<N_ROWS / 256, 256, 0, stream>>>(minv_ws, mini_ws, idx_ws, counts, out + ENC_OFF);
    vq_quant_loss_kernel<<<2048, 256, 0, stream>>>(xin, emb, idx_ws, out, acc);
    vq_finalize_kernel<<<1, 256, 0, stream>>>(counts, acc, out);
}